// Round 1
// baseline (190.568 us; speedup 1.0000x reference)
//
#include <hip/hip_runtime.h>
#include <math.h>

#define NN 8
#define CC 20
#define PP 8732
#define MM 16
#define THRESH 0.5f
#define NPR 3

#define BLK 1024
#define NW (BLK / 64)

__global__ __launch_bounds__(BLK) void mbox_row_kernel(
    const float* __restrict__ locs,    // (N,C,P,4)
    const float* __restrict__ scores,  // (N,C,P,2)
    const float* __restrict__ boxes,   // (N,C,M,4)
    const int*   __restrict__ labels,  // (N,C,M)
    const float* __restrict__ priors,  // (P,4) cxcywh
    float* __restrict__ stats)         // (N*C, 4): npos, l1, conf_pos, conf_hard
{
    __shared__ float s_ov[PP];
    __shared__ float s_ce[PP];
    __shared__ unsigned char s_obj[PP];
    __shared__ float s_bx1[MM], s_by1[MM], s_bx2[MM], s_by2[MM], s_area[MM];
    __shared__ float s_bcx[MM], s_bcy[MM], s_bw[MM], s_bh[MM];
    __shared__ int   s_lab[MM];
    __shared__ float s_wv[NW * MM];
    __shared__ int   s_wp[NW * MM];
    __shared__ int   s_pfo[MM];
    __shared__ float s_rf[NW * 3];
    __shared__ int   s_ri[NW];
    __shared__ unsigned int s_hist[256];
    __shared__ unsigned int s_prefix;
    __shared__ unsigned int s_Kr;
    __shared__ int s_Ksh;

    const int row  = blockIdx.x;
    const int tid  = threadIdx.x;
    const int lane = tid & 63;
    const int wav  = tid >> 6;

    const float4* pri4 = (const float4*)priors;
    const float4* loc4 = (const float4*)(locs + (size_t)row * PP * 4);
    const float2* sc2  = (const float2*)(scores + (size_t)row * PP * 2);
    const float*  bx   = boxes + (size_t)row * MM * 4;
    const int*    lb   = labels + (size_t)row * MM;

    if (tid < MM) {
        float x1 = bx[tid * 4 + 0], y1 = bx[tid * 4 + 1];
        float x2 = bx[tid * 4 + 2], y2 = bx[tid * 4 + 3];
        s_bx1[tid] = x1; s_by1[tid] = y1; s_bx2[tid] = x2; s_by2[tid] = y2;
        s_area[tid] = (x2 - x1) * (y2 - y1);
        s_bcx[tid] = (x1 + x2) * 0.5f;
        s_bcy[tid] = (y1 + y2) * 0.5f;
        s_bw[tid]  = x2 - x1;
        s_bh[tid]  = y2 - y1;
        s_lab[tid] = lb[tid];
    }
    __syncthreads();

    // ---------- Phase 1: IoU matching ----------
    float bestv[MM];
    int   bestp[MM];
#pragma unroll
    for (int m = 0; m < MM; m++) { bestv[m] = -1.0f; bestp[m] = 0x7fffffff; }

    for (int p = tid; p < PP; p += BLK) {
        float4 pr = pri4[p];
        float px1 = pr.x - pr.z * 0.5f;
        float py1 = pr.y - pr.w * 0.5f;
        float px2 = pr.x + pr.z * 0.5f;
        float py2 = pr.y + pr.w * 0.5f;
        float area_b = (px2 - px1) * (py2 - py1);
        float bov = -1.0f;
        int   bm  = 0;
#pragma unroll
        for (int m = 0; m < MM; m++) {
            float dx = fminf(s_bx2[m], px2) - fmaxf(s_bx1[m], px1);
            float dy = fminf(s_by2[m], py2) - fmaxf(s_by1[m], py1);
            dx = fmaxf(dx, 0.0f);
            dy = fmaxf(dy, 0.0f);
            float inter = dx * dy;
            float iou = inter / (s_area[m] + area_b - inter);
            if (iou > bov) { bov = iou; bm = m; }           // first-max over m
            if (iou > bestv[m]) { bestv[m] = iou; bestp[m] = p; } // first-max over p (p ascending per thread)
        }
        s_ov[p]  = bov;
        s_obj[p] = (unsigned char)bm;
    }

    // per-object argmax over P: wave shuffle reduce, then cross-wave
#pragma unroll
    for (int m = 0; m < MM; m++) {
        float v = bestv[m];
        int   pp = bestp[m];
#pragma unroll
        for (int off = 32; off; off >>= 1) {
            float v2 = __shfl_down(v, off);
            int   p2 = __shfl_down(pp, off);
            if (v2 > v || (v2 == v && p2 < pp)) { v = v2; pp = p2; }
        }
        if (lane == 0) { s_wv[wav * MM + m] = v; s_wp[wav * MM + m] = pp; }
    }
    __syncthreads();
    if (tid < MM) {
        float v = -2.0f;
        int pp = 0x7fffffff;
        for (int w = 0; w < NW; w++) {
            float v2 = s_wv[w * MM + tid];
            int   p2 = s_wp[w * MM + tid];
            if (v2 > v || (v2 == v && p2 < pp)) { v = v2; pp = p2; }
        }
        s_pfo[tid] = pp;
    }
    __syncthreads();
    // force: sequential, last-wins (numpy fancy-assignment semantics)
    if (tid == 0) {
        for (int m = 0; m < MM; m++) {
            int p = s_pfo[m];
            s_obj[p] = (unsigned char)m;
            s_ov[p]  = 1.0f;
        }
    }
    __syncthreads();

    // ---------- Phase 2: CE + L1 + ce_neg ----------
    float l_np = 0.0f, l_l1 = 0.0f, l_cp = 0.0f;
    for (int p = tid; p < PP; p += BLK) {
        float ov = s_ov[p];
        int   m  = s_obj[p];
        int cls = (ov < THRESH) ? 0 : s_lab[m];
        float2 sc = sc2[p];
        float mx  = fmaxf(sc.x, sc.y);
        float lse = mx + logf(expf(sc.x - mx) + expf(sc.y - mx));
        float ce  = lse - (cls ? sc.y : sc.x);
        if (cls) {
            float4 pr = pri4[p];
            float4 pl = loc4[p];
            float tx = (s_bcx[m] - pr.x) / (pr.z / 10.0f);
            float ty = (s_bcy[m] - pr.y) / (pr.w / 10.0f);
            float tw = logf(s_bw[m] / pr.z) * 5.0f;
            float th = logf(s_bh[m] / pr.w) * 5.0f;
            l_l1 += fabsf(pl.x - tx) + fabsf(pl.y - ty) + fabsf(pl.z - tw) + fabsf(pl.w - th);
            l_np += 1.0f;
            l_cp += ce;
            s_ce[p] = 0.0f;
        } else {
            s_ce[p] = fmaxf(ce, 0.0f);  // clamp keeps bit-order == value-order
        }
    }
#pragma unroll
    for (int off = 32; off; off >>= 1) {
        l_np += __shfl_down(l_np, off);
        l_l1 += __shfl_down(l_l1, off);
        l_cp += __shfl_down(l_cp, off);
    }
    if (lane == 0) { s_rf[wav * 3 + 0] = l_np; s_rf[wav * 3 + 1] = l_l1; s_rf[wav * 3 + 2] = l_cp; }
    __syncthreads();
    if (tid == 0) {
        float np = 0.0f, l1 = 0.0f, cp = 0.0f;
        for (int w = 0; w < NW; w++) { np += s_rf[w * 3]; l1 += s_rf[w * 3 + 1]; cp += s_rf[w * 3 + 2]; }
        stats[row * 4 + 0] = np;
        stats[row * 4 + 1] = l1;
        stats[row * 4 + 2] = cp;
        int K = NPR * (int)(np + 0.5f);
        s_Ksh = K;
        s_prefix = 0u;
        s_Kr = (unsigned int)(K > 0 ? K : 0);
    }
    __syncthreads();
    const int K = s_Ksh;

    // ---------- Phase 3: radix-select top-K sum of s_ce ----------
    unsigned int pivot = 0u;
    if (K > 0 && K < PP) {
        for (int pass = 0; pass < 4; pass++) {
            const int shift = 24 - 8 * pass;
            if (tid < 256) s_hist[tid] = 0u;
            __syncthreads();
            const unsigned int pref   = s_prefix;
            const unsigned int maskhi = (pass == 0) ? 0u : (0xffffffffu << (shift + 8));
            for (int p = tid; p < PP; p += BLK) {
                unsigned int u = __float_as_uint(s_ce[p]);
                if ((u & maskhi) == pref) atomicAdd(&s_hist[(u >> shift) & 255u], 1u);
            }
            __syncthreads();
            if (wav == 0) {
                unsigned int Kr = s_Kr;
                unsigned int h0 = s_hist[lane * 4 + 0];
                unsigned int h1 = s_hist[lane * 4 + 1];
                unsigned int h2 = s_hist[lane * 4 + 2];
                unsigned int h3 = s_hist[lane * 4 + 3];
                unsigned int c3 = h3;
                unsigned int c2 = h3 + h2;
                unsigned int c1 = c2 + h1;
                unsigned int c0 = c1 + h0;
                // inclusive suffix-sum of per-lane totals across the wave
                unsigned int suf = c0;
#pragma unroll
                for (int off = 1; off < 64; off <<= 1) {
                    unsigned int o = __shfl_down(suf, off);
                    if (lane + off < 64) suf += o;
                }
                unsigned int above = suf - c0;  // count in bins of strictly higher lanes
                int cand = -1;
                unsigned int G = 0;  // count strictly greater than candidate bin
                if      (c3 + above >= Kr) { cand = lane * 4 + 3; G = above + c3 - h3; }
                else if (c2 + above >= Kr) { cand = lane * 4 + 2; G = above + c2 - h2; }
                else if (c1 + above >= Kr) { cand = lane * 4 + 1; G = above + c1 - h1; }
                else if (c0 + above >= Kr) { cand = lane * 4 + 0; G = above + c0 - h0; }
                int best = cand;
#pragma unroll
                for (int off = 32; off; off >>= 1) best = max(best, __shfl_down(best, off));
                best = __shfl(best, 0);
                if (cand == best && cand >= 0) {
                    s_Kr = Kr - G;
                    s_prefix = pref | ((unsigned int)best << shift);
                }
            }
            __syncthreads();
        }
        pivot = s_prefix;
    } else {
        pivot = 0u;  // K >= PP: sum all strictly-positive values; ties at 0 add 0
    }

    // final pass: sum strictly greater than pivot + ties * pivot
    float sgt = 0.0f;
    int   cgt = 0;
    for (int p = tid; p < PP; p += BLK) {
        float v = s_ce[p];
        if (__float_as_uint(v) > pivot) { sgt += v; cgt++; }
    }
#pragma unroll
    for (int off = 32; off; off >>= 1) {
        sgt += __shfl_down(sgt, off);
        cgt += __shfl_down(cgt, off);
    }
    if (lane == 0) { s_rf[wav * 3] = sgt; s_ri[wav] = cgt; }
    __syncthreads();
    if (tid == 0) {
        float s = 0.0f;
        int cnt = 0;
        for (int w = 0; w < NW; w++) { s += s_rf[w * 3]; cnt += s_ri[w]; }
        float chard = (K <= 0) ? 0.0f : (s + (float)(K - cnt) * __uint_as_float(pivot));
        stats[row * 4 + 3] = chard;
    }
}

__global__ void mbox_finalize(const float* __restrict__ stats, float* __restrict__ out) {
    int c = threadIdx.x;
    float loss = 0.0f;
    if (c < CC) {
        float np = 0.0f, l1 = 0.0f, cp = 0.0f, ch = 0.0f;
        for (int n = 0; n < NN; n++) {
            const float* s = stats + ((size_t)(n * CC + c)) * 4;
            np += s[0]; l1 += s[1]; cp += s[2]; ch += s[3];
        }
        float loc  = l1 / fmaxf(np * 4.0f, 1.0f);
        float val  = (np > 0.0f) ? (cp + ch + 1.0f /*ALPHA*/ * loc) / fmaxf(np, 1.0f) : 0.0f;
        loss = val / (float)CC;
    }
#pragma unroll
    for (int off = 32; off; off >>= 1) loss += __shfl_down(loss, off);
    if (threadIdx.x == 0) out[0] = loss;
}

extern "C" void kernel_launch(void* const* d_in, const int* in_sizes, int n_in,
                              void* d_out, int out_size, void* d_ws, size_t ws_size,
                              hipStream_t stream) {
    const float* locs   = (const float*)d_in[0];
    const float* scores = (const float*)d_in[1];
    const float* boxes  = (const float*)d_in[2];
    const int*   labels = (const int*)d_in[3];
    const float* priors = (const float*)d_in[4];
    float* out   = (float*)d_out;
    float* stats = (float*)d_ws;  // 160*4 floats

    mbox_row_kernel<<<NN * CC, BLK, 0, stream>>>(locs, scores, boxes, labels, priors, stats);
    mbox_finalize<<<1, 64, 0, stream>>>(stats, out);
}

// Round 2
// 142.062 us; speedup vs baseline: 1.3414x; 1.3414x over previous
//
#include <hip/hip_runtime.h>
#include <math.h>

#define NN 8
#define CC 20
#define PP 8732
#define MM 16
#define NPR 3
#define SPLIT 8
#define CH 1092              // ceil(PP/SPLIT)
#define HALFB 0x3f000000u    // __float_as_uint(0.5f)
#define ROWS (NN * CC)

__device__ __forceinline__ float lse2(float a, float b) {
    float mx = fmaxf(a, b);
    return mx + logf(expf(a - mx) + expf(b - mx));
}

// ---------------- Kernel A: IoU matching + pre-force stats ----------------
#define ABLK 256
__global__ __launch_bounds__(ABLK) void mbox_p1(
    const float* __restrict__ locs, const float* __restrict__ scores,
    const float* __restrict__ boxes, const int* __restrict__ labels,
    const float* __restrict__ priors,
    unsigned int* __restrict__ packed, unsigned long long* __restrict__ partials,
    float* __restrict__ cstats)
{
    const int row = blockIdx.x / SPLIT;
    const int chunk = blockIdx.x - row * SPLIT;
    const int tid = threadIdx.x, lane = tid & 63, wav = tid >> 6;
    __shared__ float s_bx1[MM], s_by1[MM], s_bx2[MM], s_by2[MM], s_area[MM];
    __shared__ float s_bcx[MM], s_bcy[MM], s_bw[MM], s_bh[MM];
    __shared__ int s_lab[MM];
    __shared__ unsigned long long s_pk[4 * MM];
    __shared__ float s_rf[4 * 3];

    if (tid < MM) {
        const float* b = boxes + ((size_t)row * MM + tid) * 4;
        float x1 = b[0], y1 = b[1], x2 = b[2], y2 = b[3];
        s_bx1[tid] = x1; s_by1[tid] = y1; s_bx2[tid] = x2; s_by2[tid] = y2;
        s_area[tid] = (x2 - x1) * (y2 - y1);
        s_bcx[tid] = (x1 + x2) * 0.5f; s_bcy[tid] = (y1 + y2) * 0.5f;
        s_bw[tid] = x2 - x1; s_bh[tid] = y2 - y1;
        s_lab[tid] = labels[row * MM + tid];
    }
    __syncthreads();

    const float4* pri4 = (const float4*)priors;
    const float4* loc4 = (const float4*)(locs + (size_t)row * PP * 4);
    const float2* sc2  = (const float2*)(scores + (size_t)row * PP * 2);
    unsigned int* pk   = packed + (size_t)row * PP;

    float bestv[MM]; int bestp[MM];
#pragma unroll
    for (int m = 0; m < MM; m++) { bestv[m] = -1.0f; bestp[m] = 0x7fffffff; }
    float l_np = 0.0f, l_l1 = 0.0f, l_cp = 0.0f;
    const int p0 = chunk * CH, p1 = min(p0 + CH, PP);

    for (int p = p0 + tid; p < p1; p += ABLK) {
        float4 pr = pri4[p];
        float px1 = pr.x - pr.z * 0.5f, py1 = pr.y - pr.w * 0.5f;
        float px2 = pr.x + pr.z * 0.5f, py2 = pr.y + pr.w * 0.5f;
        float area_b = (px2 - px1) * (py2 - py1);
        float bov = -1.0f; int bm = 0;
#pragma unroll
        for (int m = 0; m < MM; m++) {
            float dx = fminf(s_bx2[m], px2) - fmaxf(s_bx1[m], px1);
            float dy = fminf(s_by2[m], py2) - fmaxf(s_by1[m], py1);
            dx = fmaxf(dx, 0.0f); dy = fmaxf(dy, 0.0f);
            float inter = dx * dy;
            float iou = inter / (s_area[m] + area_b - inter);
            if (iou > bov) { bov = iou; bm = m; }            // first-max over m
            if (iou > bestv[m]) { bestv[m] = iou; bestp[m] = p; } // first-max over p
        }
        pk[p] = (__float_as_uint(bov) & ~31u) | (unsigned)bm;
        if (bov >= 0.5f && s_lab[bm] != 0) {
            float2 sc = sc2[p];
            l_cp += lse2(sc.x, sc.y) - sc.y;
            l_np += 1.0f;
            float4 pl = loc4[p];
            float tx = (s_bcx[bm] - pr.x) * 10.0f / pr.z;
            float ty = (s_bcy[bm] - pr.y) * 10.0f / pr.w;
            float tw = logf(s_bw[bm] / pr.z) * 5.0f;
            float th = logf(s_bh[bm] / pr.w) * 5.0f;
            l_l1 += fabsf(pl.x - tx) + fabsf(pl.y - ty) + fabsf(pl.z - tw) + fabsf(pl.w - th);
        }
    }

    // per-object argmax: pack (valbits, 0x7fffffff-p) so u64-max == (max val, min p)
#pragma unroll
    for (int m = 0; m < MM; m++) {
        unsigned long long key =
            ((unsigned long long)__float_as_uint(bestv[m]) << 32) |
            (unsigned)(0x7fffffff - bestp[m]);
#pragma unroll
        for (int off = 32; off; off >>= 1) {
            unsigned long long o = __shfl_down(key, off);
            if (o > key) key = o;
        }
        if (lane == 0) s_pk[wav * MM + m] = key;
    }
#pragma unroll
    for (int off = 32; off; off >>= 1) {
        l_np += __shfl_down(l_np, off);
        l_l1 += __shfl_down(l_l1, off);
        l_cp += __shfl_down(l_cp, off);
    }
    if (lane == 0) { s_rf[wav * 3] = l_np; s_rf[wav * 3 + 1] = l_l1; s_rf[wav * 3 + 2] = l_cp; }
    __syncthreads();
    if (tid < MM) {
        unsigned long long key = s_pk[tid];
        for (int w = 1; w < 4; w++) {
            unsigned long long o = s_pk[w * MM + tid];
            if (o > key) key = o;
        }
        partials[((size_t)row * MM + tid) * SPLIT + chunk] = key;
    }
    if (tid == 0) {
        float np = 0, l1 = 0, cp = 0;
        for (int w = 0; w < 4; w++) { np += s_rf[w * 3]; l1 += s_rf[w * 3 + 1]; cp += s_rf[w * 3 + 2]; }
        float* cs = cstats + ((size_t)row * SPLIT + chunk) * 3;
        cs[0] = np; cs[1] = l1; cs[2] = cp;
    }
}

// ---------------- Kernel B: reduce argmax, apply force as deltas ----------------
__global__ __launch_bounds__(64) void mbox_force(
    const float* __restrict__ locs, const float* __restrict__ scores,
    const float* __restrict__ boxes, const int* __restrict__ labels,
    const float* __restrict__ priors, unsigned int* __restrict__ packed,
    const unsigned long long* __restrict__ partials,
    const float* __restrict__ cstats, float* __restrict__ rstats)
{
    const int row = blockIdx.x, tid = threadIdx.x;
    __shared__ float s_bcx[MM], s_bcy[MM], s_bw[MM], s_bh[MM];
    __shared__ int s_lab[MM], s_pfo[MM];
    __shared__ float s_sum[3];
    if (tid < MM) {
        const float* b = boxes + ((size_t)row * MM + tid) * 4;
        float x1 = b[0], y1 = b[1], x2 = b[2], y2 = b[3];
        s_bcx[tid] = (x1 + x2) * 0.5f; s_bcy[tid] = (y1 + y2) * 0.5f;
        s_bw[tid] = x2 - x1; s_bh[tid] = y2 - y1;
        s_lab[tid] = labels[row * MM + tid];
        unsigned long long key = partials[((size_t)row * MM + tid) * SPLIT];
        for (int c2 = 1; c2 < SPLIT; c2++) {
            unsigned long long o = partials[((size_t)row * MM + tid) * SPLIT + c2];
            if (o > key) key = o;
        }
        s_pfo[tid] = 0x7fffffff - (int)(unsigned)(key & 0xffffffffull);
    }
    if (tid >= 16 && tid < 19) {
        int j = tid - 16; float s = 0;
        for (int c2 = 0; c2 < SPLIT; c2++) s += cstats[((size_t)row * SPLIT + c2) * 3 + j];
        s_sum[j] = s;
    }
    __syncthreads();

    const float4* pri4 = (const float4*)priors;
    const float4* loc4 = (const float4*)(locs + (size_t)row * PP * 4);
    const float2* sc2  = (const float2*)(scores + (size_t)row * PP * 2);
    unsigned int* pk   = packed + (size_t)row * PP;

    // sequential last-wins == group by prior, keep only the largest m per prior
    float d_np = 0, d_l1 = 0, d_cp = 0;
    int p = -1; bool is_last = false;
    if (tid < MM) {
        p = s_pfo[tid];
        is_last = true;
        for (int mm = tid + 1; mm < MM; mm++) if (s_pfo[mm] == p) is_last = false;
        if (is_last) {
            unsigned int u = pk[p];
            float4 pr = pri4[p];
            float4 pl = loc4[p];
            float2 sc = sc2[p];
            float lse = lse2(sc.x, sc.y);
            int mo = u & 31;
            bool po = ((u & ~31u) >= HALFB) && (s_lab[mo] != 0);
            if (po) {  // remove old positive contribution
                d_np -= 1.0f; d_cp -= (lse - sc.y);
                float tx = (s_bcx[mo] - pr.x) * 10.0f / pr.z;
                float ty = (s_bcy[mo] - pr.y) * 10.0f / pr.w;
                float tw = logf(s_bw[mo] / pr.z) * 5.0f;
                float th = logf(s_bh[mo] / pr.w) * 5.0f;
                d_l1 -= fabsf(pl.x - tx) + fabsf(pl.y - ty) + fabsf(pl.z - tw) + fabsf(pl.w - th);
            }
            if (s_lab[tid] != 0) {  // add forced positive contribution (ov=1.0)
                d_np += 1.0f; d_cp += (lse - sc.y);
                float tx = (s_bcx[tid] - pr.x) * 10.0f / pr.z;
                float ty = (s_bcy[tid] - pr.y) * 10.0f / pr.w;
                float tw = logf(s_bw[tid] / pr.z) * 5.0f;
                float th = logf(s_bh[tid] / pr.w) * 5.0f;
                d_l1 += fabsf(pl.x - tx) + fabsf(pl.y - ty) + fabsf(pl.z - tw) + fabsf(pl.w - th);
            }
        }
    }
    __syncthreads();  // all reads of pk[] done before writes
    if (tid < MM && is_last) pk[p] = 0x3f800000u | (unsigned)tid;  // pack(ov=1.0, m)

#pragma unroll
    for (int off = 32; off; off >>= 1) {
        d_np += __shfl_down(d_np, off);
        d_l1 += __shfl_down(d_l1, off);
        d_cp += __shfl_down(d_cp, off);
    }
    if (tid == 0) {
        float* rs = rstats + (size_t)row * 8;
        rs[0] = s_sum[0] + d_np;
        rs[1] = s_sum[1] + d_l1;
        rs[2] = s_sum[2] + d_cp;
    }
}

// ---------------- Kernel C: ce_neg + radix-select top-K ----------------
#define CBLK 1024
#define CNW 16
__global__ __launch_bounds__(CBLK) void mbox_sel(
    const float* __restrict__ scores, const int* __restrict__ labels,
    const unsigned int* __restrict__ packed, float* __restrict__ rstats)
{
    const int row = blockIdx.x, tid = threadIdx.x, lane = tid & 63, wav = tid >> 6;
    __shared__ float s_ce[PP];
    __shared__ int s_lab[MM];
    __shared__ unsigned int s_hist[256];
    __shared__ unsigned int s_prefix, s_Kr;
    __shared__ int s_Ksh;
    __shared__ float s_rf[CNW];
    __shared__ int s_ri[CNW];

    if (tid < MM) s_lab[tid] = labels[row * MM + tid];
    if (tid == 0) {
        float np = rstats[(size_t)row * 8];
        int K = NPR * (int)(np + 0.5f);
        s_Ksh = K; s_prefix = 0u; s_Kr = (unsigned)(K > 0 ? K : 0);
    }
    __syncthreads();

    const float2* sc2 = (const float2*)(scores + (size_t)row * PP * 2);
    const unsigned int* pk = packed + (size_t)row * PP;
    for (int p = tid; p < PP; p += CBLK) {
        unsigned int u = pk[p];
        float2 sc = sc2[p];
        int m = u & 31;
        bool pos = ((u & ~31u) >= HALFB) && (s_lab[m] != 0);
        s_ce[p] = pos ? 0.0f : fmaxf(lse2(sc.x, sc.y) - sc.x, 0.0f);
    }
    __syncthreads();
    const int K = s_Ksh;

    unsigned int pivot = 0u;
    if (K > 0 && K < PP) {
        for (int pass = 0; pass < 4; pass++) {
            const int shift = 24 - 8 * pass;
            if (tid < 256) s_hist[tid] = 0u;
            __syncthreads();
            const unsigned int pref   = s_prefix;
            const unsigned int maskhi = (pass == 0) ? 0u : (0xffffffffu << (shift + 8));
            for (int p = tid; p < PP; p += CBLK) {
                unsigned int u = __float_as_uint(s_ce[p]);
                if ((u & maskhi) == pref) atomicAdd(&s_hist[(u >> shift) & 255u], 1u);
            }
            __syncthreads();
            if (wav == 0) {
                unsigned int Kr = s_Kr;
                unsigned int h0 = s_hist[lane * 4 + 0];
                unsigned int h1 = s_hist[lane * 4 + 1];
                unsigned int h2 = s_hist[lane * 4 + 2];
                unsigned int h3 = s_hist[lane * 4 + 3];
                unsigned int c3 = h3;
                unsigned int c2 = h3 + h2;
                unsigned int c1 = c2 + h1;
                unsigned int c0 = c1 + h0;
                unsigned int suf = c0;
#pragma unroll
                for (int off = 1; off < 64; off <<= 1) {
                    unsigned int o = __shfl_down(suf, off);
                    if (lane + off < 64) suf += o;
                }
                unsigned int above = suf - c0;
                int cand = -1;
                unsigned int G = 0;
                if      (c3 + above >= Kr) { cand = lane * 4 + 3; G = above + c3 - h3; }
                else if (c2 + above >= Kr) { cand = lane * 4 + 2; G = above + c2 - h2; }
                else if (c1 + above >= Kr) { cand = lane * 4 + 1; G = above + c1 - h1; }
                else if (c0 + above >= Kr) { cand = lane * 4 + 0; G = above + c0 - h0; }
                int best = cand;
#pragma unroll
                for (int off = 32; off; off >>= 1) best = max(best, __shfl_down(best, off));
                best = __shfl(best, 0);
                if (cand == best && cand >= 0) {
                    s_Kr = Kr - G;
                    s_prefix = pref | ((unsigned int)best << shift);
                }
            }
            __syncthreads();
        }
        pivot = s_prefix;
    }

    float sgt = 0.0f; int cgt = 0;
    for (int p = tid; p < PP; p += CBLK) {
        float v = s_ce[p];
        if (__float_as_uint(v) > pivot) { sgt += v; cgt++; }
    }
#pragma unroll
    for (int off = 32; off; off >>= 1) {
        sgt += __shfl_down(sgt, off);
        cgt += __shfl_down(cgt, off);
    }
    if (lane == 0) { s_rf[wav] = sgt; s_ri[wav] = cgt; }
    __syncthreads();
    if (tid == 0) {
        float s = 0; int cnt = 0;
        for (int w = 0; w < CNW; w++) { s += s_rf[w]; cnt += s_ri[w]; }
        float chard = (K <= 0) ? 0.0f : (s + (float)(K - cnt) * __uint_as_float(pivot));
        rstats[(size_t)row * 8 + 4] = chard;
    }
}

// ---------------- Kernel D: final cross-row reduction ----------------
__global__ void mbox_finalize(const float* __restrict__ rstats, float* __restrict__ out) {
    int c = threadIdx.x;
    float loss = 0.0f;
    if (c < CC) {
        float np = 0, l1 = 0, cp = 0, ch = 0;
        for (int n = 0; n < NN; n++) {
            const float* s = rstats + ((size_t)(n * CC + c)) * 8;
            np += s[0]; l1 += s[1]; cp += s[2]; ch += s[4];
        }
        float loc = l1 / fmaxf(np * 4.0f, 1.0f);
        float val = (np > 0.0f) ? (cp + ch + loc) / fmaxf(np, 1.0f) : 0.0f;
        loss = val / (float)CC;
    }
#pragma unroll
    for (int off = 32; off; off >>= 1) loss += __shfl_down(loss, off);
    if (threadIdx.x == 0) out[0] = loss;
}

extern "C" void kernel_launch(void* const* d_in, const int* in_sizes, int n_in,
                              void* d_out, int out_size, void* d_ws, size_t ws_size,
                              hipStream_t stream) {
    const float* locs   = (const float*)d_in[0];
    const float* scores = (const float*)d_in[1];
    const float* boxes  = (const float*)d_in[2];
    const int*   labels = (const int*)d_in[3];
    const float* priors = (const float*)d_in[4];
    float* out = (float*)d_out;

    char* ws = (char*)d_ws;
    unsigned int* packed        = (unsigned int*)ws;                       // 5,588,480 B
    unsigned long long* partials= (unsigned long long*)(ws + 5588480);     //   163,840 B
    float* cstats               = (float*)(ws + 5588480 + 163840);         //    15,360 B
    float* rstats               = (float*)(ws + 5588480 + 163840 + 15360); //     5,120 B

    mbox_p1<<<ROWS * SPLIT, ABLK, 0, stream>>>(locs, scores, boxes, labels, priors,
                                               packed, partials, cstats);
    mbox_force<<<ROWS, 64, 0, stream>>>(locs, scores, boxes, labels, priors,
                                        packed, partials, cstats, rstats);
    mbox_sel<<<ROWS, CBLK, 0, stream>>>(scores, labels, packed, rstats);
    mbox_finalize<<<1, 64, 0, stream>>>(rstats, out);
}